// Round 4
// baseline (139.927 us; speedup 1.0000x reference)
//
#include <hip/hip_runtime.h>

typedef short bf16x8 __attribute__((ext_vector_type(8)));
typedef float f32x4 __attribute__((ext_vector_type(4)));
typedef unsigned short us4 __attribute__((ext_vector_type(4)));

#define S_LEN 2048
#define HIDD 1024
#define NH 16
#define HD 64

#define BK 64

static __device__ __forceinline__ unsigned short f2bf(float f) {
  union { float f; unsigned u; } v; v.f = f;
  unsigned r = v.u + 0x7FFFu + ((v.u >> 16) & 1u);  // RNE
  return (unsigned short)(r >> 16);
}

static __device__ __forceinline__ unsigned cvtpk(float lo, float hi) {
  unsigned r;
  asm("v_cvt_pk_bf16_f32 %0, %1, %2" : "=v"(r) : "v"(lo), "v"(hi));
  return r;
}

static __device__ __forceinline__ float ex2(float x) {
#if __has_builtin(__builtin_amdgcn_exp2f)
  return __builtin_amdgcn_exp2f(x);
#else
  return __expf(x * 0.69314718056f);
#endif
}

#define GLD16(gp, lp)                                                        \
  __builtin_amdgcn_global_load_lds(                                         \
      (const __attribute__((address_space(1))) void*)(gp),                  \
      (__attribute__((address_space(3))) void*)(lp), 16, 0, 0)

// ---------------- f32 -> bf16 conversion for hs + 4 weights ----------------
__global__ __launch_bounds__(256) void cvt5_kernel(
    const float* __restrict__ s0, const float* __restrict__ s1, const float* __restrict__ s2,
    const float* __restrict__ s3, const float* __restrict__ s4,
    unsigned short* __restrict__ d0, unsigned short* __restrict__ d1,
    unsigned short* __restrict__ d2, unsigned short* __restrict__ d3,
    unsigned short* __restrict__ d4) {
  const float* s; unsigned short* d; int n4;
  switch (blockIdx.y) {
    case 0: s = s0; d = d0; n4 = (2 * S_LEN * HIDD) / 4; break;
    case 1: s = s1; d = d1; n4 = (HIDD * HIDD) / 4; break;
    case 2: s = s2; d = d2; n4 = (HIDD * HIDD) / 4; break;
    case 3: s = s3; d = d3; n4 = (HIDD * HIDD) / 4; break;
    default: s = s4; d = d4; n4 = (HIDD * HIDD) / 4; break;
  }
  for (int i = blockIdx.x * blockDim.x + threadIdx.x; i < n4;
       i += gridDim.x * blockDim.x) {
    float4 v = ((const float4*)s)[i];
    us4 o;
    o.x = f2bf(v.x); o.y = f2bf(v.y); o.z = f2bf(v.z); o.w = f2bf(v.w);
    ((us4*)d)[i] = o;
  }
}

// ---------------- mask -> bitmask [S][S/32] u32 ----------------
__global__ __launch_bounds__(256) void maskbits_kernel(
    const unsigned char* __restrict__ m8, unsigned* __restrict__ bits) {
  int idx = blockIdx.x * 256 + threadIdx.x;  // 2048*64 = 131072
  int q = idx >> 6, w = idx & 63;
  bool bytemode = (m8[1] != 0);
  unsigned r = 0;
  if (bytemode) {
    const uint4* p = (const uint4*)(m8 + (size_t)q * 2048 + w * 32);
    uint4 a = p[0], b = p[1];
    unsigned v[8] = {a.x, a.y, a.z, a.w, b.x, b.y, b.z, b.w};
#pragma unroll
    for (int j = 0; j < 8; ++j)
#pragma unroll
      for (int k = 0; k < 4; ++k)
        r |= (((v[j] >> (k * 8)) & 255u) ? 1u : 0u) << (j * 4 + k);
  } else {
    const int4* p = (const int4*)((const int*)m8 + (size_t)q * 2048 + (size_t)w * 32);
#pragma unroll
    for (int j = 0; j < 8; ++j) {
      int4 v = p[j];
      r |= (v.x ? 1u : 0u) << (j * 4 + 0);
      r |= (v.y ? 1u : 0u) << (j * 4 + 1);
      r |= (v.z ? 1u : 0u) << (j * 4 + 2);
      r |= (v.w ? 1u : 0u) << (j * 4 + 3);
    }
  }
  bits[idx] = r;
}

// ---------------- GEMM core v2: GLD16 staging + XOR-chunk swizzle ----------
template <int MFRAG>
static __device__ __forceinline__ void gemm_core2(
    const unsigned short* __restrict__ A, const unsigned short* __restrict__ W,
    int bm0, int bn0, unsigned short* As, unsigned short* Bs,
    f32x4 (&acc)[MFRAG][4]) {
  const int tid = threadIdx.x;
  const int lane = tid & 63;
  const int wid = tid >> 6;
  const int wr = wid >> 1, wc = wid & 1;
  const int l15 = lane & 15, g = lane >> 4, l7 = l15 & 7;
  const int ra = (g ^ l7) * 8;  // kk=0 chunk offset (shorts); kk=1 -> ^32

  for (int k0 = 0; k0 < HIDD; k0 += BK) {
    __syncthreads();
#pragma unroll
    for (int it = 0; it < MFRAG; ++it) {
      int p = it * 256 + tid;
      int r = p >> 3, ch = (p & 7) ^ (r & 7);
      GLD16(A + (size_t)(bm0 + r) * HIDD + k0 + ch * 8,
            As + (it * 256 + wid * 64) * 8);
    }
#pragma unroll
    for (int it = 0; it < 4; ++it) {
      int p = it * 256 + tid;
      int r = p >> 3, ch = (p & 7) ^ (r & 7);
      GLD16(W + (size_t)(bn0 + r) * HIDD + k0 + ch * 8,
            Bs + (it * 256 + wid * 64) * 8);
    }
    __syncthreads();
#pragma unroll
    for (int kk = 0; kk < 2; ++kk) {
      bf16x8 af[MFRAG], bfr[4];
#pragma unroll
      for (int m = 0; m < MFRAG; ++m)
        af[m] = *(const bf16x8*)&As[(wr * (MFRAG * 16) + m * 16 + l15) * 64 + (ra ^ (kk * 32))];
#pragma unroll
      for (int n = 0; n < 4; ++n)
        bfr[n] = *(const bf16x8*)&Bs[(wc * 64 + n * 16 + l15) * 64 + (ra ^ (kk * 32))];
#pragma unroll
      for (int m = 0; m < MFRAG; ++m)
#pragma unroll
        for (int n = 0; n < 4; ++n)
          acc[m][n] = __builtin_amdgcn_mfma_f32_16x16x32_bf16(af[m], bfr[n], acc[m][n], 0, 0, 0);
    }
  }
}

// ---------------- QKV projection (z=0:Q scaled log2e/8, 1:K, 2:V->VT) ------
__global__ __launch_bounds__(256) void gemm_qkv(
    const unsigned short* __restrict__ hs,
    const unsigned short* __restrict__ Wq, const unsigned short* __restrict__ Wk,
    const unsigned short* __restrict__ Wv,
    const float* __restrict__ bq, const float* __restrict__ bk, const float* __restrict__ bv,
    unsigned short* __restrict__ Qs, unsigned short* __restrict__ Kb,
    unsigned short* __restrict__ VT) {
  __shared__ __align__(16) unsigned short As[128 * 64];
  __shared__ __align__(16) unsigned short Bs[128 * 64];
  const int z = blockIdx.z;
  const unsigned short* W = (z == 0) ? Wq : ((z == 1) ? Wk : Wv);
  const float* bias = (z == 0) ? bq : ((z == 1) ? bk : bv);

  f32x4 acc[4][4];
#pragma unroll
  for (int m = 0; m < 4; ++m)
#pragma unroll
    for (int n = 0; n < 4; ++n) acc[m][n] = (f32x4){0.f, 0.f, 0.f, 0.f};

  const int bm0 = blockIdx.x * 128, bn0 = blockIdx.y * 128;
  gemm_core2<4>(hs, W, bm0, bn0, As, Bs, acc);

  const int lane = threadIdx.x & 63;
  const int wid = threadIdx.x >> 6;
  const int wr = wid >> 1, wc = wid & 1;
  const int l15 = lane & 15, g = lane >> 4;
  const float qscale = 0.125f * 1.44269504088896f;  // 1/sqrt(64) * log2(e): exp2 softmax

#pragma unroll
  for (int m = 0; m < 4; ++m) {
#pragma unroll
    for (int n = 0; n < 4; ++n) {
      int grow0 = bm0 + wr * 64 + m * 16 + g * 4;
      int gcol = bn0 + wc * 64 + n * 16 + l15;
      float bv_ = bias[gcol];
      if (z == 0) {
#pragma unroll
        for (int i = 0; i < 4; ++i)
          Qs[(size_t)(grow0 + i) * HIDD + gcol] = f2bf((acc[m][n][i] + bv_) * qscale);
      } else if (z == 1) {
#pragma unroll
        for (int i = 0; i < 4; ++i)
          Kb[(size_t)(grow0 + i) * HIDD + gcol] = f2bf(acc[m][n][i] + bv_);
      } else {
        int b = grow0 >> 11, s = grow0 & 2047;
        int h = gcol >> 6, d = gcol & 63;
        us4 pk;
#pragma unroll
        for (int i = 0; i < 4; ++i) pk[i] = f2bf(acc[m][n][i] + bv_);
        *(us4*)&VT[((size_t)(b * NH + h) * HD + d) * S_LEN + s] = pk;
      }
    }
  }
}

// ---------------- output projection: f32 result, BM=64 (512 blocks) --------
__global__ __launch_bounds__(256) void gemm_o(
    const unsigned short* __restrict__ ctx, const unsigned short* __restrict__ Wo,
    const float* __restrict__ bo, float* __restrict__ out) {
  __shared__ __align__(16) unsigned short As[64 * 64];
  __shared__ __align__(16) unsigned short Bs[128 * 64];
  f32x4 acc[2][4];
#pragma unroll
  for (int m = 0; m < 2; ++m)
#pragma unroll
    for (int n = 0; n < 4; ++n) acc[m][n] = (f32x4){0.f, 0.f, 0.f, 0.f};

  const int bm0 = blockIdx.x * 64, bn0 = blockIdx.y * 128;
  gemm_core2<2>(ctx, Wo, bm0, bn0, As, Bs, acc);

  const int lane = threadIdx.x & 63;
  const int wid = threadIdx.x >> 6;
  const int wr = wid >> 1, wc = wid & 1;
  const int l15 = lane & 15, g = lane >> 4;
#pragma unroll
  for (int m = 0; m < 2; ++m) {
#pragma unroll
    for (int n = 0; n < 4; ++n) {
      int grow0 = bm0 + wr * 32 + m * 16 + g * 4;
      int gcol = bn0 + wc * 64 + n * 16 + l15;
      float bv_ = bo[gcol];
#pragma unroll
      for (int i = 0; i < 4; ++i)
        out[(size_t)(grow0 + i) * HIDD + gcol] = acc[m][n][i] + bv_;
    }
  }
}

// ---------------- flash attention v4 ----------------
// grid (bh=32, qblk=16), 512 thr / 8 waves; wave = 16 q rows; KVBLK=64 dbuf.
// exp2-domain softmax (Q pre-scaled log2e/8), unmasked running max,
// defer-max THR=8 (log2 units), pointer-increment GLD16 staging (no guard:
// 33rd prefetch lands in allocated ws, never consumed), max3 tree, cvt_pk.
__global__ __launch_bounds__(512) void attn4_kernel(
    const unsigned short* __restrict__ Qs, const unsigned short* __restrict__ Kb,
    const unsigned short* __restrict__ VT, const unsigned* __restrict__ mbits,
    unsigned short* __restrict__ ctx) {
  __shared__ __align__(16) unsigned short Kt[2][4096];  // [buf][row*64 + ch*8]
  __shared__ __align__(16) unsigned short Vt[2][4096];
  __shared__ __align__(16) unsigned short Pl[8][16][72];

  const int tid = threadIdx.x;
  const int wid = tid >> 6, lane = tid & 63;
  const int l15 = lane & 15, g = lane >> 4;
  const int l7 = l15 & 7;
  const int b = blockIdx.x >> 4, h = blockIdx.x & 15;
  const int qrow = blockIdx.y * 128 + wid * 16 + l15;

  const unsigned short* Kbh = Kb + (size_t)b * S_LEN * HIDD + h * HD;
  const unsigned short* VTbh = VT + (size_t)(b * NH + h) * HD * S_LEN;

  const unsigned short* Qrow = Qs + (size_t)(b * S_LEN + qrow) * HIDD + h * HD;
  bf16x8 qf0 = *(const bf16x8*)(Qrow + g * 8);
  bf16x8 qf1 = *(const bf16x8*)(Qrow + 32 + g * 8);

  const unsigned* mrow = mbits + (size_t)qrow * 64;

  const int rb0 = l15 * 64 + ((g ^ l7)) * 8;
  const int rb1 = l15 * 64 + ((g ^ l7) ^ 4) * 8;

  // ---- staging pointers: computed once, incremented by constant per iter ----
  const bool isK = (wid < 4);
  const int wk = wid & 3;
  {
  }
  int p0 = wk * 128 + lane;            // (wk*2+0)*64 + lane
  int p1 = p0 + 64;
  int r0 = p0 >> 3, c0 = (p0 & 7) ^ (r0 & 7);
  int r1 = p1 >> 3, c1 = (p1 & 7) ^ (r1 & 7);
  const unsigned short* gp0;
  const unsigned short* gp1;
  int gstep;
  unsigned short* lp0;
  if (isK) {
    gp0 = Kbh + (size_t)r0 * HIDD + c0 * 8;
    gp1 = Kbh + (size_t)r1 * HIDD + c1 * 8;
    gstep = 64 * HIDD;
    lp0 = &Kt[0][0] + wk * 1024;
  } else {
    gp0 = VTbh + (size_t)r0 * S_LEN + c0 * 8;
    gp1 = VTbh + (size_t)r1 * S_LEN + c1 * 8;
    gstep = 64;
    lp0 = &Vt[0][0] + wk * 1024;
  }
  unsigned short* lp1 = lp0 + 512;

  float m_run = -1e8f, l_run = 0.f;
  f32x4 oacc[4];
#pragma unroll
  for (int dc = 0; dc < 4; ++dc) oacc[dc] = (f32x4){0.f, 0.f, 0.f, 0.f};

  // prologue: stage tile 0 into buf 0
  GLD16(gp0, lp0);
  GLD16(gp1, lp1);
  gp0 += gstep; gp1 += gstep;
  uint2 mw = *(const uint2*)mrow;
  __syncthreads();

  for (int it = 0; it < 32; ++it) {
    const int tb = ((it + 1) & 1) * 4096;  // prefetch target buf (shorts)
    GLD16(gp0, lp0 + tb);
    GLD16(gp1, lp1 + tb);
    gp0 += gstep; gp1 += gstep;
    uint2 mw_n = *(const uint2*)(mrow + (it + 1) * 2);  // last read unused, in-bounds ws

    // S^T tiles (raw, unmasked)
    const unsigned short* Kbuf = &Kt[it & 1][0];
    f32x4 sacc[4];
#pragma unroll
    for (int t = 0; t < 4; ++t) {
      sacc[t] = (f32x4){0.f, 0.f, 0.f, 0.f};
      bf16x8 ka = *(const bf16x8*)(Kbuf + t * 1024 + rb0);
      bf16x8 kb2 = *(const bf16x8*)(Kbuf + t * 1024 + rb1);
      sacc[t] = __builtin_amdgcn_mfma_f32_16x16x32_bf16(ka, qf0, sacc[t], 0, 0, 0);
      sacc[t] = __builtin_amdgcn_mfma_f32_16x16x32_bf16(kb2, qf1, sacc[t], 0, 0, 0);
    }

    // raw column max, max3-shaped tree (triples fuse to v_max3_f32)
    float t0 = fmaxf(fmaxf(sacc[0][0], sacc[0][1]), sacc[0][2]);
    float t1 = fmaxf(fmaxf(sacc[0][3], sacc[1][0]), sacc[1][1]);
    float t2 = fmaxf(fmaxf(sacc[1][2], sacc[1][3]), sacc[2][0]);
    float t3 = fmaxf(fmaxf(sacc[2][1], sacc[2][2]), sacc[2][3]);
    float t4 = fmaxf(fmaxf(sacc[3][0], sacc[3][1]), sacc[3][2]);
    float t5 = fmaxf(fmaxf(t0, t1), sacc[3][3]);
    float pmax = fmaxf(fmaxf(fmaxf(t2, t3), t4), t5);
    pmax = fmaxf(pmax, __shfl_xor(pmax, 16));
    pmax = fmaxf(pmax, __shfl_xor(pmax, 32));

    // defer-max (THR = 8 in log2 units -> P bounded by 256, f32/bf16 safe)
    if (__any(pmax > m_run + 8.0f)) {
      float m_new = fmaxf(m_run, pmax);
      float corr = ex2(m_run - m_new);
      l_run *= corr;
#pragma unroll
      for (int dc = 0; dc < 4; ++dc) oacc[dc] *= corr;
      m_run = m_new;
    }

    float lsum = 0.f;
#pragma unroll
    for (int t = 0; t < 4; ++t) {
      unsigned word = (t & 2) ? mw.y : mw.x;
      unsigned nib = word >> ((t & 1) * 16 + g * 4);
      float e0 = ex2(sacc[t][0] - m_run);
      float e1 = ex2(sacc[t][1] - m_run);
      float e2 = ex2(sacc[t][2] - m_run);
      float e3 = ex2(sacc[t][3] - m_run);
      float q0 = (nib & 1u) ? e0 : 0.f;
      float q1 = (nib & 2u) ? e1 : 0.f;
      float q2 = (nib & 4u) ? e2 : 0.f;
      float q3 = (nib & 8u) ? e3 : 0.f;
      lsum += (q0 + q1) + (q2 + q3);
      uint2 w2;
      w2.x = cvtpk(q0, q1);
      w2.y = cvtpk(q2, q3);
      *(uint2*)&Pl[wid][l15][t * 16 + g * 4] = w2;
    }
    lsum += __shfl_xor(lsum, 16);
    lsum += __shfl_xor(lsum, 32);
    l_run += lsum;

    bf16x8 pf0 = *(const bf16x8*)&Pl[wid][l15][g * 8];
    bf16x8 pf1 = *(const bf16x8*)&Pl[wid][l15][32 + g * 8];

    const unsigned short* Vbuf = &Vt[it & 1][0];
#pragma unroll
    for (int dc = 0; dc < 4; ++dc) {
      bf16x8 va = *(const bf16x8*)(Vbuf + dc * 1024 + rb0);
      bf16x8 vb = *(const bf16x8*)(Vbuf + dc * 1024 + rb1);
      oacc[dc] = __builtin_amdgcn_mfma_f32_16x16x32_bf16(va, pf0, oacc[dc], 0, 0, 0);
      oacc[dc] = __builtin_amdgcn_mfma_f32_16x16x32_bf16(vb, pf1, oacc[dc], 0, 0, 0);
    }

    mw = mw_n;
    __syncthreads();
  }

  float inv_l = 1.f / l_run;
  unsigned short* crow = ctx + (size_t)(b * S_LEN + qrow) * HIDD + h * HD;
#pragma unroll
  for (int dc = 0; dc < 4; ++dc) {
    uint2 o;
    o.x = cvtpk(oacc[dc][0] * inv_l, oacc[dc][1] * inv_l);
    o.y = cvtpk(oacc[dc][2] * inv_l, oacc[dc][3] * inv_l);
    *(uint2*)&crow[dc * 16 + g * 4] = o;
  }
}

extern "C" void kernel_launch(void* const* d_in, const int* in_sizes, int n_in,
                              void* d_out, int out_size, void* d_ws, size_t ws_size,
                              hipStream_t stream) {
  const float* hs = (const float*)d_in[0];
  const float* Wq = (const float*)d_in[1];
  const float* bq = (const float*)d_in[2];
  const float* Wk = (const float*)d_in[3];
  const float* bk = (const float*)d_in[4];
  const float* Wv = (const float*)d_in[5];
  const float* bv = (const float*)d_in[6];
  const float* Wo = (const float*)d_in[7];
  const float* bo = (const float*)d_in[8];
  const unsigned char* mask = (const unsigned char*)d_in[9];

  char* ws = (char*)d_ws;
  unsigned short* hs_bf = (unsigned short*)(ws);               // 8 MB (dead after gemm_qkv)
  unsigned short* Wq_bf = (unsigned short*)(ws + (8u << 20));  // 2 MB
  unsigned short* Wk_bf = (unsigned short*)(ws + (10u << 20));
  unsigned short* Wv_bf = (unsigned short*)(ws + (12u << 20));
  unsigned short* Wo_bf = (unsigned short*)(ws + (14u << 20));
  unsigned short* Qs    = (unsigned short*)(ws + (16u << 20)); // 8 MB (scaled log2e/8)
  unsigned short* Kbf   = (unsigned short*)(ws + (24u << 20)); // 8 MB
  unsigned short* VT    = (unsigned short*)(ws + (32u << 20)); // 8 MB [b,h,d,s]
  unsigned short* ctxb  = (unsigned short*)(ws + (40u << 20)); // 8 MB
  unsigned* mbits = (unsigned*)(ws);  // 512 KB, overwrites hs_bf AFTER gemm_qkv
  float* out = (float*)d_out;

  cvt5_kernel<<<dim3(256, 5), 256, 0, stream>>>(hs, Wq, Wk, Wv, Wo,
                                                hs_bf, Wq_bf, Wk_bf, Wv_bf, Wo_bf);
  gemm_qkv<<<dim3(32, 8, 3), 256, 0, stream>>>(hs_bf, Wq_bf, Wk_bf, Wv_bf,
                                               bq, bk, bv, Qs, Kbf, VT);
  maskbits_kernel<<<512, 256, 0, stream>>>(mask, mbits);
  attn4_kernel<<<dim3(32, 16), 512, 0, stream>>>(Qs, Kbf, VT, mbits, ctxb);
  gemm_o<<<dim3(64, 8), 256, 0, stream>>>(ctxb, Wo_bf, bo, out);
}